// Round 6
// baseline (532.452 us; speedup 1.0000x reference)
//
#include <hip/hip_runtime.h>

#define E_NUM 12000
#define D_DIM 6272
#define H_DIM 256
#define M1 24000

typedef __attribute__((ext_vector_type(8))) short short8;
typedef __attribute__((ext_vector_type(8))) __bf16 bf16x8;
typedef __attribute__((ext_vector_type(4))) float f32x4;

__device__ __forceinline__ float silu_f(float x) {
  return x / (1.0f + __expf(-x));
}

__device__ __forceinline__ bf16x8 ld_frag(const short* p) {
  return __builtin_bit_cast(bf16x8, *(const short8*)p);
}

// pack bf16x8 from two f32x4 (slots 0-3 from a, 4-7 from b); RNE via native cast
__device__ __forceinline__ bf16x8 cvt8(f32x4 a, f32x4 b) {
  bf16x8 r;
#pragma unroll
  for (int j = 0; j < 4; ++j) {
    r[j] = (__bf16)a[j];
    r[4 + j] = (__bf16)b[j];
  }
  return r;
}

// ---- P1 pack (k-permuted): P1[(kt*256 + col)*32 + p] = bf(W1[kt*32 + phys(p)][col])
// phys(p) = (p>>3)*4 + (p&3) + ((p>>2)&1)*16  — matches gemm1's contiguous A lane loads.
__global__ void pack_p1(const float* __restrict__ W1, short* __restrict__ P1) {
  const int kt = blockIdx.x;   // 0..195
  const int col = threadIdx.x; // 0..255
  const float* src = W1 + (size_t)kt * 32 * H_DIM + col;
  short8 s0, s1, s2, s3;
#pragma unroll
  for (int j = 0; j < 8; ++j) {
    {
      const int p = j;
      const int phys = ((p >> 3) << 2) + (p & 3) + (((p >> 2) & 1) << 4);
      s0[j] = __builtin_bit_cast(short, (__bf16)src[(size_t)phys * H_DIM]);
    }
    {
      const int p = 8 + j;
      const int phys = ((p >> 3) << 2) + (p & 3) + (((p >> 2) & 1) << 4);
      s1[j] = __builtin_bit_cast(short, (__bf16)src[(size_t)phys * H_DIM]);
    }
    {
      const int p = 16 + j;
      const int phys = ((p >> 3) << 2) + (p & 3) + (((p >> 2) & 1) << 4);
      s2[j] = __builtin_bit_cast(short, (__bf16)src[(size_t)phys * H_DIM]);
    }
    {
      const int p = 24 + j;
      const int phys = ((p >> 3) << 2) + (p & 3) + (((p >> 2) & 1) << 4);
      s3[j] = __builtin_bit_cast(short, (__bf16)src[(size_t)phys * H_DIM]);
    }
  }
  short* dst = P1 + ((size_t)kt * H_DIM + col) * 32;
  *(short8*)(dst + 0) = s0;
  *(short8*)(dst + 8) = s1;
  *(short8*)(dst + 16) = s2;
  *(short8*)(dst + 24) = s3;
}

// ---- P2 pack (linear k): P2[(kt*D_DIM + col)*32 + p] = bf(W2[kt*32 + p][col])
__global__ void pack_p2(const float* __restrict__ W2, short* __restrict__ P2) {
  const int kt = blockIdx.y;                      // 0..7
  const int col = blockIdx.x * 128 + threadIdx.x; // 0..6271
  const float* src = W2 + (size_t)kt * 32 * D_DIM + col;
  short* dst = P2 + ((size_t)kt * D_DIM + col) * 32;
#pragma unroll
  for (int c = 0; c < 4; ++c) {
    short8 s;
#pragma unroll
    for (int j = 0; j < 8; ++j)
      s[j] = __builtin_bit_cast(short, (__bf16)src[(size_t)(c * 8 + j) * D_DIM]);
    *(short8*)(dst + c * 8) = s;
  }
}

// -------- GEMM1 v6: ZERO barriers, ZERO LDS. 1-wave blocks, 32 rows x 128 cols. --------
// A fp32 direct-to-reg (k-permuted contiguous lane loads), B from P1 (1KB frags, L2).
// depth-2 A prefetch, depth-1 B. hg written in panel layout hgp[(panel*M1+row)*32+c].
#define G1_KS (D_DIM / 32)  // 196

#define LOADA(DST, IT)                                              \
  do {                                                              \
    DST[0][0] = *(const f32x4*)(arow0 + (size_t)(IT)*32);           \
    DST[0][1] = *(const f32x4*)(arow0 + (size_t)(IT)*32 + 16);      \
    DST[1][0] = *(const f32x4*)(arow1 + (size_t)(IT)*32);           \
    DST[1][1] = *(const f32x4*)(arow1 + (size_t)(IT)*32 + 16);      \
  } while (0)

__launch_bounds__(64, 2)
__global__ void gemm1_kernel(const float* __restrict__ node_embed,
                             const float* __restrict__ ori,
                             const float* __restrict__ x_edge_c,
                             const short* __restrict__ P1,
                             const float* __restrict__ b1,
                             short* __restrict__ hgp) {
  const int bid = blockIdx.x;  // 0..1499
  const int strip = bid >> 1;  // 32-row strip (0..749)
  const int wn = bid & 1;      // 128-col half
  const int lane = threadIdx.x;
  const int l15 = lane & 15;
  const int lq = lane >> 4;
  const int m_base = strip * 32;

  const float* xb = (strip < (E_NUM / 32))
                        ? (node_embed + (size_t)m_base * D_DIM)
                        : (ori + (size_t)(m_base - E_NUM) * D_DIM);
  // lane loads 16B at row (m*16+l15), float offset it*32 + lq*4 (+16)
  const float* arow0 = xb + (size_t)l15 * D_DIM + lq * 4;
  const float* arow1 = xb + (size_t)(16 + l15) * D_DIM + lq * 4;
  // B frag n at kstep it: bbase + it*8192 + n*512  (1KB contiguous per frag)
  const short* bbase = P1 + ((size_t)wn * 128 + l15) * 32 + lq * 8;

  f32x4 acc[2][8];
#pragma unroll
  for (int m = 0; m < 2; ++m)
#pragma unroll
    for (int n = 0; n < 8; ++n) acc[m][n] = (f32x4){0.f, 0.f, 0.f, 0.f};

  f32x4 A0[2][2], A1[2][2], A2[2][2];
  bf16x8 Bc[8], Bn[8];

  LOADA(A0, 0);
  LOADA(A1, 1);
#pragma unroll
  for (int n = 0; n < 8; ++n) Bc[n] = ld_frag(bbase + n * 512);

#pragma unroll 4
  for (int it = 0; it < G1_KS; ++it) {
    // issue next-tile loads: B(it+1) first (L2, needed sooner), A(it+2) second (HBM)
    if (it + 1 < G1_KS) {
#pragma unroll
      for (int n = 0; n < 8; ++n)
        Bn[n] = ld_frag(bbase + (size_t)(it + 1) * 8192 + n * 512);
    }
    if (it + 2 < G1_KS) LOADA(A2, it + 2);

    // convert current A (loaded 2 iters ago) and compute
    bf16x8 af0 = cvt8(A0[0][0], A0[0][1]);
    bf16x8 af1 = cvt8(A0[1][0], A0[1][1]);
#pragma unroll
    for (int n = 0; n < 8; ++n) {
      acc[0][n] = __builtin_amdgcn_mfma_f32_16x16x32_bf16(af0, Bc[n], acc[0][n], 0, 0, 0);
      acc[1][n] = __builtin_amdgcn_mfma_f32_16x16x32_bf16(af1, Bc[n], acc[1][n], 0, 0, 0);
    }

    // rotate
#pragma unroll
    for (int m = 0; m < 2; ++m)
#pragma unroll
      for (int h = 0; h < 2; ++h) {
        A0[m][h] = A1[m][h];
        A1[m][h] = A2[m][h];
      }
#pragma unroll
    for (int n = 0; n < 8; ++n) Bc[n] = Bn[n];
  }

  // epilogue: bias + silu + gate -> hgp panel layout
#pragma unroll
  for (int n = 0; n < 8; ++n) {
    const int col = wn * 128 + n * 16 + l15;
    const float b1v = b1[col];
    const int panel = wn * 4 + (n >> 1);
    const int cin = (n & 1) * 16 + l15;
#pragma unroll
    for (int m = 0; m < 2; ++m) {
#pragma unroll
      for (int i = 0; i < 4; ++i) {
        const int gmr = m_base + m * 16 + lq * 4 + i;
        const int e = (gmr < E_NUM) ? gmr : gmr - E_NUM;
        float v = acc[m][n][i] + b1v;
        v = silu_f(v) * x_edge_c[(size_t)e * H_DIM + col];
        hgp[((size_t)panel * M1 + gmr) * 32 + cin] =
            __builtin_bit_cast(short, (__bf16)v);
      }
    }
  }
}

// -------- GEMM2 v4: ZERO barriers, ZERO LDS. 1-wave blocks, 16 e-rows x 128 d-cols. ----
// out[e] = silu(hg[e]@W2+b2) + silu(hg[e+E]@W2+b2); A from hgp panels, B from P2 panels.
__launch_bounds__(64, 2)
__global__ void gemm2_kernel(const short* __restrict__ hgp,
                             const short* __restrict__ P2,
                             const float* __restrict__ b2,
                             float* __restrict__ out) {
  const int dx = blockIdx.x;  // 0..48 -> d0 = dx*128
  const int ey = blockIdx.y;  // 0..749 -> e0 = ey*16
  const int lane = threadIdx.x;
  const int l15 = lane & 15;
  const int lq = lane >> 4;
  const int e0 = ey * 16;
  const int d0 = dx * 128;

  const short* abase0 = hgp + ((size_t)(e0 + l15)) * 32 + lq * 8;
  const short* abase1 = hgp + ((size_t)(E_NUM + e0 + l15)) * 32 + lq * 8;
  const short* bbase = P2 + ((size_t)d0 + l15) * 32 + lq * 8;

  f32x4 acc[2][8];
#pragma unroll
  for (int h = 0; h < 2; ++h)
#pragma unroll
    for (int n = 0; n < 8; ++n) acc[h][n] = (f32x4){0.f, 0.f, 0.f, 0.f};

  bf16x8 Ac0, Ac1, An0, An1, Bc[8], Bn[8];
  Ac0 = ld_frag(abase0);
  Ac1 = ld_frag(abase1);
#pragma unroll
  for (int n = 0; n < 8; ++n) Bc[n] = ld_frag(bbase + n * 512);

#pragma unroll
  for (int kt = 0; kt < 8; ++kt) {
    if (kt < 7) {
#pragma unroll
      for (int n = 0; n < 8; ++n)
        Bn[n] = ld_frag(bbase + (size_t)(kt + 1) * (D_DIM * 32) + n * 512);
      An0 = ld_frag(abase0 + (size_t)(kt + 1) * (M1 * 32));
      An1 = ld_frag(abase1 + (size_t)(kt + 1) * (M1 * 32));
    }
#pragma unroll
    for (int n = 0; n < 8; ++n) {
      acc[0][n] = __builtin_amdgcn_mfma_f32_16x16x32_bf16(Ac0, Bc[n], acc[0][n], 0, 0, 0);
      acc[1][n] = __builtin_amdgcn_mfma_f32_16x16x32_bf16(Ac1, Bc[n], acc[1][n], 0, 0, 0);
    }
    if (kt < 7) {
      Ac0 = An0;
      Ac1 = An1;
#pragma unroll
      for (int n = 0; n < 8; ++n) Bc[n] = Bn[n];
    }
  }

#pragma unroll
  for (int n = 0; n < 8; ++n) {
    const int cold = d0 + n * 16 + l15;
    const float b2v = b2[cold];
#pragma unroll
    for (int i = 0; i < 4; ++i) {
      const int e = e0 + lq * 4 + i;
      out[(size_t)e * D_DIM + cold] =
          silu_f(acc[0][n][i] + b2v) + silu_f(acc[1][n][i] + b2v);
    }
  }
}

extern "C" void kernel_launch(void* const* d_in, const int* in_sizes, int n_in,
                              void* d_out, int out_size, void* d_ws, size_t ws_size,
                              hipStream_t stream) {
  const float* node_embed = (const float*)d_in[0];
  const float* x_edge_c = (const float*)d_in[1];
  const float* ori = (const float*)d_in[2];
  const float* W1 = (const float*)d_in[3];
  const float* b1 = (const float*)d_in[4];
  const float* W2 = (const float*)d_in[5];
  const float* b2 = (const float*)d_in[6];
  float* out_p = (float*)d_out;

  char* ws = (char*)d_ws;
  short* P1 = (short*)ws;                   // [196][256][32] bf16 = 3,211,264 B
  short* P2 = (short*)(ws + 3211264);       // [8][6272][32] bf16 = 3,211,264 B
  short* hgp = (short*)(ws + 2 * 3211264);  // [8][24000][32] bf16 = 12,288,000 B

  pack_p1<<<dim3(D_DIM / 32), 256, 0, stream>>>(W1, P1);
  pack_p2<<<dim3(D_DIM / 128, 8), 128, 0, stream>>>(W2, P2);

  gemm1_kernel<<<dim3(1500), 64, 0, stream>>>(node_embed, ori, x_edge_c, P1, b1, hgp);

  gemm2_kernel<<<dim3(D_DIM / 128, E_NUM / 16), 64, 0, stream>>>(hgp, P2, b2, out_p);
}

// Round 7
// 436.244 us; speedup vs baseline: 1.2205x; 1.2205x over previous
//
#include <hip/hip_runtime.h>

#define E_NUM 12000
#define D_DIM 6272
#define H_DIM 256
#define M1 24000

typedef __attribute__((ext_vector_type(8))) short short8;
typedef __attribute__((ext_vector_type(8))) __bf16 bf16x8;
typedef __attribute__((ext_vector_type(4))) float f32x4;

__device__ __forceinline__ float silu_f(float x) {
  return x / (1.0f + __expf(-x));
}

__device__ __forceinline__ bf16x8 ld_frag(const short* p) {
  return __builtin_bit_cast(bf16x8, *(const short8*)p);
}

__device__ __forceinline__ bf16x8 cvt8(f32x4 a, f32x4 b) {
  bf16x8 r;
#pragma unroll
  for (int j = 0; j < 4; ++j) {
    r[j] = (__bf16)a[j];
    r[4 + j] = (__bf16)b[j];
  }
  return r;
}

// async global->LDS, 16B/lane; LDS dest = wave-uniform base + lane*16 (linear)
__device__ __forceinline__ void gll16(const void* g, void* l) {
  __builtin_amdgcn_global_load_lds(
      (const __attribute__((address_space(1))) void*)g,
      (__attribute__((address_space(3))) void*)l, 16, 0, 0);
}

// ---- P1 pack (linear k): P1[(kt*256 + col)*32 + p] = bf(W1[kt*32 + p][col]) ----
__global__ void pack_p1(const float* __restrict__ W1, short* __restrict__ P1) {
  const int kt = blockIdx.x;    // 0..195
  const int col = threadIdx.x;  // 0..255
  const float* src = W1 + (size_t)kt * 32 * H_DIM + col;
  short* dst = P1 + ((size_t)kt * H_DIM + col) * 32;
#pragma unroll
  for (int c = 0; c < 4; ++c) {
    short8 s;
#pragma unroll
    for (int j = 0; j < 8; ++j)
      s[j] = __builtin_bit_cast(short, (__bf16)src[(size_t)(c * 8 + j) * H_DIM]);
    *(short8*)(dst + c * 8) = s;
  }
}

// ---- P2 pack (linear k): P2[(kt*D_DIM + col)*32 + p] = bf(W2[kt*32 + p][col]) ----
__global__ void pack_p2(const float* __restrict__ W2, short* __restrict__ P2) {
  const int kt = blockIdx.y;                       // 0..7
  const int col = blockIdx.x * 128 + threadIdx.x;  // 0..6271
  const float* src = W2 + (size_t)kt * 32 * D_DIM + col;
  short* dst = P2 + ((size_t)kt * D_DIM + col) * 32;
#pragma unroll
  for (int c = 0; c < 4; ++c) {
    short8 s;
#pragma unroll
    for (int j = 0; j < 8; ++j)
      s[j] = __builtin_bit_cast(short, (__bf16)src[(size_t)(c * 8 + j) * D_DIM]);
    *(short8*)(dst + c * 8) = s;
  }
}

// ================== GEMM1 v7: m97-structure, gll A (fp32), panel B ==================
// x = concat(node_embed, ori) [24000][6272] fp32; P1 [196][256][32] bf16.
// BM=32, BN=256, BK=64; 256 thr = 4 waves, wave wn owns cols wn*64..+63.
// A LDS: [2][32 rows][64 fp32] linear; 32B-granule g of row r stored at g^(r&7)
// (achieved by pre-swizzling the GLOBAL source; LDS dest stays linear for gll).
#define G1_ST 98
__launch_bounds__(256, 3)
__global__ void gemm1_kernel(const float* __restrict__ node_embed,
                             const float* __restrict__ ori,
                             const float* __restrict__ x_edge_c,
                             const short* __restrict__ P1,
                             const float* __restrict__ b1,
                             short* __restrict__ hgp) {
  __shared__ __align__(16) float Als[2][32 * 64];  // 2 x 8 KB

  const int t = threadIdx.x;
  const int wn = t >> 6;
  const int lane = t & 63;
  const int l15 = lane & 15;
  const int lq = lane >> 4;
  const int m_base = blockIdx.x * 32;

  const float* xb = (m_base < E_NUM) ? (node_embed + (size_t)m_base * D_DIM)
                                     : (ori + (size_t)(m_base - E_NUM) * D_DIM);

  // staging: round r (0/1): dest float idx = t*4 + r*1024 -> row R=(t>>4)+r*16, chunk=t&15
  // logical chunk cl = ((chunk>>1) ^ (R&7))*2 + (chunk&1); R&7 identical for both rounds
  const int R0 = t >> 4;   // 0..15
  const int cst = t & 15;  // 16B chunk
  const int cl = ((((cst >> 1) ^ (R0 & 7)) << 1) | (cst & 1));
  const float* asrc0 = xb + (size_t)R0 * D_DIM + cl * 4;
  const float* asrc1 = xb + (size_t)(R0 + 16) * D_DIM + cl * 4;

  // B fragment base: col = wn*64 + n*16 + l15, k-slot lq*8 -> 1KB contiguous frags
  const short* bbase = P1 + (size_t)(wn * 64 + l15) * 32 + lq * 8;

  const int asw = l15 & 7;

  f32x4 acc[2][4];
#pragma unroll
  for (int m = 0; m < 2; ++m)
#pragma unroll
    for (int n = 0; n < 4; ++n) acc[m][n] = (f32x4){0.f, 0.f, 0.f, 0.f};

  // prologue: stage tile 0 into buf 0
  gll16(asrc0, &Als[0][t * 4]);
  gll16(asrc1, &Als[0][t * 4 + 1024]);
  __syncthreads();

  int cur = 0;
  for (int it = 0; it < G1_ST; ++it) {
    const int nxt = cur ^ 1;
    if (it + 1 < G1_ST) {
      const size_t ko = (size_t)(it + 1) * 64;
      gll16(asrc0 + ko, &Als[nxt][t * 4]);
      gll16(asrc1 + ko, &Als[nxt][t * 4 + 1024]);
    }
    // B frags for this step (k-tiles it*2, it*2+1), straight from L2
    bf16x8 bq[2][4];
    {
      const short* bs = bbase + (size_t)it * 16384;
#pragma unroll
      for (int ks = 0; ks < 2; ++ks)
#pragma unroll
        for (int n = 0; n < 4; ++n) bq[ks][n] = ld_frag(bs + ks * 8192 + n * 512);
    }
    // A frags from LDS (fp32 -> bf16 at read time)
    bf16x8 af[2][2];
    {
      const float* Ac = &Als[cur][0];
#pragma unroll
      for (int m = 0; m < 2; ++m)
#pragma unroll
        for (int ks = 0; ks < 2; ++ks) {
          const int fidx = (m * 16 + l15) * 64 + (((ks * 4 + lq) ^ asw) * 8);
          f32x4 lo = *(const f32x4*)(Ac + fidx);
          f32x4 hi = *(const f32x4*)(Ac + fidx + 4);
          af[m][ks] = cvt8(lo, hi);
        }
    }
#pragma unroll
    for (int ks = 0; ks < 2; ++ks)
#pragma unroll
      for (int m = 0; m < 2; ++m)
#pragma unroll
        for (int n = 0; n < 4; ++n)
          acc[m][n] = __builtin_amdgcn_mfma_f32_16x16x32_bf16(af[m][ks], bq[ks][n],
                                                              acc[m][n], 0, 0, 0);
    __syncthreads();  // drains gll (vmcnt) -> buf[nxt] ready; protects buffer reuse
    cur = nxt;
  }

  // epilogue: bias + silu + gate -> hgp panel layout [8][24000][32]
#pragma unroll
  for (int n = 0; n < 4; ++n) {
    const int col = wn * 64 + n * 16 + l15;
    const float b1v = b1[col];
    const int panel = wn * 2 + (n >> 1);
    const int cin = (n & 1) * 16 + l15;
#pragma unroll
    for (int m = 0; m < 2; ++m) {
#pragma unroll
      for (int i = 0; i < 4; ++i) {
        const int gmr = m_base + m * 16 + lq * 4 + i;
        const int e = (gmr < E_NUM) ? gmr : gmr - E_NUM;
        float v = acc[m][n][i] + b1v;
        v = silu_f(v) * x_edge_c[(size_t)e * H_DIM + col];
        hgp[((size_t)panel * M1 + gmr) * 32 + cin] = __builtin_bit_cast(short, (__bf16)v);
      }
    }
  }
}

// ================== GEMM2 v5: m97-structure, gll A (hgp panels), panel B ==================
// out[e] = silu(hg[e]@W2+b2) + silu(hg[e+E]@W2+b2)
// 64 e-rows (+64 mirrored) x 128 d-cols; K=256, BK=64 (4 steps); 256 thr, 4 waves 2x2.
// A LDS: [2][128 rows][64 bf16]; 16B-chunk c of row r stored at c^(r&7) via source swizzle.
__launch_bounds__(256, 3)
__global__ void gemm2_kernel(const short* __restrict__ hgp,
                             const short* __restrict__ P2,
                             const float* __restrict__ b2,
                             float* __restrict__ out) {
  __shared__ __align__(16) short Als[2][128 * 64];  // 2 x 16 KB

  const int t = threadIdx.x;
  const int wave = t >> 6;
  const int lane = t & 63;
  const int l15 = lane & 15;
  const int lq = lane >> 4;
  const int wr = wave >> 1;  // e-row half (32 rows)
  const int wc = wave & 1;   // d-col half (64 cols)
  const int d0 = blockIdx.x * 128;
  const int e0 = blockIdx.y * 64;

  // staging: round r (0..3): dest short idx = t*8 + r*2048 -> row R=(t>>3)+r*32, chunk=t&7
  const int R0 = t >> 3;  // 0..31
  const int cst = t & 7;
  const int cl = cst ^ (R0 & 7);  // (R&7) same for all rounds
  const short* asrc[4];
#pragma unroll
  for (int r = 0; r < 4; ++r) {
    int er = e0 + R0 + (r & 1) * 32;
    if (er >= E_NUM) er = E_NUM - 1;
    const int grow = er + (r >> 1) * E_NUM;
    // base panel (cl>>2) + per-step offset it*2 panels; within-panel short offset (cl&3)*8
    asrc[r] = hgp + (size_t)(cl >> 2) * (M1 * 32) + (size_t)grow * 32 + (cl & 3) * 8;
  }

  const short* bbase = P2 + (size_t)(d0 + wc * 64 + l15) * 32 + lq * 8;
  const int asw = l15 & 7;

  f32x4 acc[2][2][4];
#pragma unroll
  for (int h = 0; h < 2; ++h)
#pragma unroll
    for (int m = 0; m < 2; ++m)
#pragma unroll
      for (int n = 0; n < 4; ++n) acc[h][m][n] = (f32x4){0.f, 0.f, 0.f, 0.f};

  // prologue: stage k-step 0
#pragma unroll
  for (int r = 0; r < 4; ++r) gll16(asrc[r], &Als[0][t * 8 + r * 2048]);
  __syncthreads();

  int cur = 0;
#pragma unroll
  for (int it = 0; it < 4; ++it) {
    const int nxt = cur ^ 1;
    if (it < 3) {
      const size_t ko = (size_t)(it + 1) * 2 * (M1 * 32);
#pragma unroll
      for (int r = 0; r < 4; ++r) gll16(asrc[r] + ko, &Als[nxt][t * 8 + r * 2048]);
    }
    bf16x8 bq[2][4];
#pragma unroll
    for (int ks = 0; ks < 2; ++ks)
#pragma unroll
      for (int n = 0; n < 4; ++n)
        bq[ks][n] = ld_frag(bbase + (size_t)(it * 2 + ks) * (D_DIM * 32) + n * 512);

    bf16x8 af[2][2][2];
#pragma unroll
    for (int h = 0; h < 2; ++h)
#pragma unroll
      for (int m = 0; m < 2; ++m)
#pragma unroll
        for (int ks = 0; ks < 2; ++ks) {
          const int R = h * 64 + wr * 32 + m * 16 + l15;
          af[h][m][ks] = ld_frag(&Als[cur][R * 64 + (((ks * 4 + lq) ^ asw) * 8)]);
        }
#pragma unroll
    for (int ks = 0; ks < 2; ++ks)
#pragma unroll
      for (int h = 0; h < 2; ++h)
#pragma unroll
        for (int m = 0; m < 2; ++m)
#pragma unroll
          for (int n = 0; n < 4; ++n)
            acc[h][m][n] = __builtin_amdgcn_mfma_f32_16x16x32_bf16(
                af[h][m][ks], bq[ks][n], acc[h][m][n], 0, 0, 0);
    __syncthreads();
    cur = nxt;
  }

  // epilogue: bias + silu + combine halves -> fp32 out
#pragma unroll
  for (int n = 0; n < 4; ++n) {
    const int col = d0 + wc * 64 + n * 16 + l15;
    const float b2v = b2[col];
#pragma unroll
    for (int m = 0; m < 2; ++m) {
#pragma unroll
      for (int i = 0; i < 4; ++i) {
        const int e = e0 + wr * 32 + m * 16 + lq * 4 + i;
        if (e < E_NUM) {
          out[(size_t)e * D_DIM + col] =
              silu_f(acc[0][m][n][i] + b2v) + silu_f(acc[1][m][n][i] + b2v);
        }
      }
    }
  }
}

extern "C" void kernel_launch(void* const* d_in, const int* in_sizes, int n_in,
                              void* d_out, int out_size, void* d_ws, size_t ws_size,
                              hipStream_t stream) {
  const float* node_embed = (const float*)d_in[0];
  const float* x_edge_c = (const float*)d_in[1];
  const float* ori = (const float*)d_in[2];
  const float* W1 = (const float*)d_in[3];
  const float* b1 = (const float*)d_in[4];
  const float* W2 = (const float*)d_in[5];
  const float* b2 = (const float*)d_in[6];
  float* out_p = (float*)d_out;

  char* ws = (char*)d_ws;
  short* P1 = (short*)ws;                   // [196][256][32] bf16 = 3,211,264 B
  short* P2 = (short*)(ws + 3211264);       // [8][6272][32] bf16 = 3,211,264 B
  short* hgp = (short*)(ws + 2 * 3211264);  // [8][24000][32] bf16 = 12,288,000 B

  pack_p1<<<dim3(D_DIM / 32), 256, 0, stream>>>(W1, P1);
  pack_p2<<<dim3(D_DIM / 128, 8), 128, 0, stream>>>(W2, P2);

  gemm1_kernel<<<dim3(M1 / 32), 256, 0, stream>>>(node_embed, ori, x_edge_c, P1, b1, hgp);

  gemm2_kernel<<<dim3(D_DIM / 128, (E_NUM + 63) / 64), 256, 0, stream>>>(hgp, P2, b2, out_p);
}